// Round 1
// baseline (343.333 us; speedup 1.0000x reference)
//
#include <hip/hip_runtime.h>
#include <hip/hip_bf16.h>

#define DIMD 256
#define SLEN 4096
#define KT 32
#define QT 64

typedef __attribute__((ext_vector_type(8))) short short8;
typedef __attribute__((ext_vector_type(4))) float f32x4;

__device__ __forceinline__ ushort f2bf(float x) {
  union { float f; unsigned u; } v; v.f = x;
  unsigned r = v.u + 0x7fffu + ((v.u >> 16) & 1u);
  return (ushort)(r >> 16);
}

// ---------------- QKV projection: [16384,256] @ [256,768] + b ----------------
// fp32 compute (accuracy), bf16 outputs. Q,K row-major [m][256]; V stored
// TRANSPOSED Vt[b][d][s] so attention's PV B-fragments are contiguous.
__global__ __launch_bounds__(256) void qkv_proj(const float* __restrict__ X,
                                                const float* __restrict__ W,
                                                const float* __restrict__ bias,
                                                ushort* __restrict__ Qo,
                                                ushort* __restrict__ Ko,
                                                ushort* __restrict__ Vto) {
  __shared__ float Xs[64][33];   // +1 pad: a[i] column reads spread banks
  __shared__ float Ws[32][64];
  const int tid = threadIdx.x;
  const int m0 = blockIdx.x * 64;
  const int n0 = blockIdx.y * 64;
  const int tx = tid & 15, ty = tid >> 4;
  float acc[4][4] = {};
  for (int k0 = 0; k0 < 256; k0 += 32) {
    __syncthreads();
    {
      const int r = tid >> 5, c = tid & 31;
#pragma unroll
      for (int it = 0; it < 8; ++it)
        Xs[r + it * 8][c] = X[(size_t)(m0 + r + it * 8) * 256 + k0 + c];
      const int r2 = tid >> 6, c2 = tid & 63;
#pragma unroll
      for (int it = 0; it < 8; ++it)
        Ws[r2 + it * 4][c2] = W[(size_t)(k0 + r2 + it * 4) * 768 + n0 + c2];
    }
    __syncthreads();
#pragma unroll
    for (int k = 0; k < 32; ++k) {
      float a[4], bb[4];
#pragma unroll
      for (int i = 0; i < 4; ++i) a[i] = Xs[ty * 4 + i][k];
#pragma unroll
      for (int j = 0; j < 4; ++j) bb[j] = Ws[k][tx + 16 * j];
#pragma unroll
      for (int i = 0; i < 4; ++i)
#pragma unroll
        for (int j = 0; j < 4; ++j) acc[i][j] += a[i] * bb[j];
    }
  }
#pragma unroll
  for (int j = 0; j < 4; ++j) {
    const int n = n0 + tx + 16 * j;        // block-uniform segment (64 | 256)
    const float bv = bias[n];
#pragma unroll
    for (int i = 0; i < 4; ++i) {
      const int m = m0 + ty * 4 + i;
      const ushort h = f2bf(acc[i][j] + bv);
      if (n < 256)      Qo[(size_t)m * 256 + n] = h;
      else if (n < 512) Ko[(size_t)m * 256 + (n - 256)] = h;
      else {
        const int d = n - 512, bidx = m >> 12, s = m & 4095;
        Vto[((size_t)bidx * 256 + d) * 4096 + s] = h;
      }
    }
  }
}

// ---------------- flash attention: per block 64 q-rows, 4 waves ----------------
__global__ __launch_bounds__(256) void flash_attn(const ushort* __restrict__ Q,
                                                  const ushort* __restrict__ K,
                                                  const ushort* __restrict__ Vt,
                                                  float* __restrict__ Out) {
  __shared__ ushort Ks[KT][DIMD + 8];   // +16B row pad -> 2-way (free)
  __shared__ ushort Vs[DIMD][KT + 8];   // V^T tile, +16B pad
  __shared__ float  Ss[4][16][33];      // per-wave S scratch
  __shared__ ushort Ps[4][16][40];      // per-wave P (bf16), padded
  __shared__ float  m_s[4][16], l_s[4][16], f_s[4][16];

  const int tid = threadIdx.x;
  const int w = tid >> 6, lane = tid & 63;
  const int b = blockIdx.x >> 6;
  const int q0 = (blockIdx.x & 63) * QT;
  const int qa = lane & 15, hi = lane >> 4;
  const float scale = 0.0625f;  // 1/sqrt(256)

  if (lane < 16) { m_s[w][lane] = -1e30f; l_s[w][lane] = 0.f; }

  // hoist Q fragments: A row = lane&15 (verified layout), 8 d-chunks of 32
  const ushort* Qrow = Q + (size_t)(b * SLEN + q0 + w * 16 + qa) * DIMD;
  short8 qf[8];
#pragma unroll
  for (int dc = 0; dc < 8; ++dc)
    qf[dc] = *(const short8*)(Qrow + dc * 32 + hi * 8);

  f32x4 zero = {0.f, 0.f, 0.f, 0.f};
  f32x4 acc[16];
#pragma unroll
  for (int dc = 0; dc < 16; ++dc) acc[dc] = zero;

  const ushort* Kb  = K  + (size_t)b * SLEN * DIMD;
  const ushort* Vtb = Vt + (size_t)b * DIMD * SLEN;

  for (int kv0 = 0; kv0 < SLEN; kv0 += KT) {
    // ---- stage K [32][256] and V^T [256][32] into LDS (coalesced 16B loads)
    {
      const int r = tid >> 5, c8 = (tid & 31) * 8;
#pragma unroll
      for (int it = 0; it < 4; ++it) {
        short8 v = *(const short8*)(Kb + (size_t)(kv0 + r + it * 8) * DIMD + c8);
        *(short8*)&Ks[r + it * 8][c8] = v;
      }
      const int d = tid >> 2, c8v = (tid & 3) * 8;
#pragma unroll
      for (int it = 0; it < 4; ++it) {
        short8 v = *(const short8*)(Vtb + (size_t)(d + it * 64) * SLEN + kv0 + c8v);
        *(short8*)&Vs[d + it * 64][c8v] = v;
      }
    }
    __syncthreads();

    // ---- S = (Q K^T) * scale : two independent 16x16 acc chains
    f32x4 s0 = zero, s1 = zero;
#pragma unroll
    for (int dc = 0; dc < 8; ++dc) {
      short8 kf0 = *(const short8*)&Ks[qa][dc * 32 + hi * 8];
      short8 kf1 = *(const short8*)&Ks[qa + 16][dc * 32 + hi * 8];
      s0 = __builtin_amdgcn_mfma_f32_16x16x32_bf16(qf[dc], kf0, s0, 0, 0, 0);
      s1 = __builtin_amdgcn_mfma_f32_16x16x32_bf16(qf[dc], kf1, s1, 0, 0, 0);
    }
    // C layout (m89-verified): col = lane&15, row = hi*4 + r
#pragma unroll
    for (int r = 0; r < 4; ++r) {
      Ss[w][hi * 4 + r][qa]      = s0[r] * scale;
      Ss[w][hi * 4 + r][qa + 16] = s1[r] * scale;
    }

    // ---- online softmax: 4 lanes per row, 8 cols each
    const int row = lane >> 2, c0 = (lane & 3) * 8;
    float sv[8], tmax = -1e30f;
#pragma unroll
    for (int j = 0; j < 8; ++j) { sv[j] = Ss[w][row][c0 + j]; tmax = fmaxf(tmax, sv[j]); }
    tmax = fmaxf(tmax, __shfl_xor(tmax, 1));
    tmax = fmaxf(tmax, __shfl_xor(tmax, 2));
    const float mold = m_s[w][row];
    const float mnew = fmaxf(mold, tmax);
    float ssum = 0.f;
#pragma unroll
    for (int j = 0; j < 8; ++j) {
      const float p = __expf(sv[j] - mnew);
      ssum += p;
      Ps[w][row][c0 + j] = f2bf(p);
    }
    ssum += __shfl_xor(ssum, 1);
    ssum += __shfl_xor(ssum, 2);
    const float fr = __expf(mold - mnew);
    if ((lane & 3) == 0) {
      m_s[w][row] = mnew;
      l_s[w][row] = l_s[w][row] * fr + ssum;
      f_s[w][row] = fr;
    }

    // ---- rescale accumulators by exp(m_old - m_new)
    float frr[4];
#pragma unroll
    for (int r = 0; r < 4; ++r) frr[r] = f_s[w][hi * 4 + r];
#pragma unroll
    for (int dc = 0; dc < 16; ++dc)
#pragma unroll
      for (int r = 0; r < 4; ++r) acc[dc][r] *= frr[r];

    // ---- O += P @ V : one A-frag (P), 16 independent MFMAs over d-chunks
    short8 pf = *(const short8*)&Ps[w][qa][hi * 8];
#pragma unroll
    for (int dc = 0; dc < 16; ++dc) {
      short8 vf = *(const short8*)&Vs[dc * 16 + qa][hi * 8];
      acc[dc] = __builtin_amdgcn_mfma_f32_16x16x32_bf16(pf, vf, acc[dc], 0, 0, 0);
    }
    __syncthreads();
  }

  // ---- epilogue: divide by l, write fp32 output
  float inv[4];
#pragma unroll
  for (int r = 0; r < 4; ++r) inv[r] = 1.f / l_s[w][hi * 4 + r];
  float* Ob = Out + (size_t)(b * SLEN + q0 + w * 16) * DIMD;
#pragma unroll
  for (int dc = 0; dc < 16; ++dc)
#pragma unroll
    for (int r = 0; r < 4; ++r)
      Ob[(size_t)(hi * 4 + r) * DIMD + dc * 16 + qa] = acc[dc][r] * inv[r];
}

extern "C" void kernel_launch(void* const* d_in, const int* in_sizes, int n_in,
                              void* d_out, int out_size, void* d_ws, size_t ws_size,
                              hipStream_t stream) {
  const float* X    = (const float*)d_in[0];
  const float* W    = (const float*)d_in[1];
  const float* bias = (const float*)d_in[2];
  ushort* qw  = (ushort*)d_ws;                    // 8 MB
  ushort* kw  = qw + (size_t)16384 * 256;         // 8 MB
  ushort* vtw = kw + (size_t)16384 * 256;         // 8 MB (V transposed)
  qkv_proj<<<dim3(256, 12), 256, 0, stream>>>(X, W, bias, qw, kw, vtw);
  flash_attn<<<dim3(256), 256, 0, stream>>>(qw, kw, vtw, (float*)d_out);
}